// Round 12
// baseline (10313.737 us; speedup 1.0000x reference)
//
#include <hip/hip_runtime.h>
#include <stdint.h>

#define TS   1024
#define NB   32
#define DIN  512
#define HU   768
#define UPW  12          // hidden units per WG per direction (64 WGs x 12 = 768)
#define XROWB 1048       // As row stride bytes (512 fp16 + 24B pad -> distinct bank phases)
#define HROWB 1560       // Hs row stride bytes (768 fp16 + 24B pad)
#define SPIN_MAX 16384

typedef _Float16 f16x8 __attribute__((ext_vector_type(8)));
typedef float f32x4 __attribute__((ext_vector_type(4)));
typedef unsigned int u32;
typedef unsigned long long u64;
typedef u32 u32x2 __attribute__((ext_vector_type(2)));
typedef u32 u32x4 __attribute__((ext_vector_type(4)));
using gas_u32 = u32 __attribute__((address_space(1)));
using las_u32 = u32 __attribute__((address_space(3)));

__device__ __forceinline__ u32 f2h_bits(float f) {
  _Float16 h = (_Float16)f;
  return (u32)__builtin_bit_cast(unsigned short, h);
}

// ---- init: zero 2 dirs x 2 slots x 8192 u64 (tag 0 == step-0 ready; replay-safe) ----
__global__ void lstm_init_k(u64* hb) {
  hb[blockIdx.x * 256 + threadIdx.x] = 0ull;   // 128 x 256 = 32768 u64
}

// ---- transpose + fp16 convert: x[B][T][D] -> xh[T][B][D] ----
__global__ void lstm_xpose_k(const float* __restrict__ x, unsigned short* __restrict__ xh) {
  int idx = blockIdx.x * 256 + threadIdx.x;
  int d4 = idx & 127;
  int t  = (idx >> 7) & 1023;
  int b  = idx >> 17;
  float4 v = *(const float4*)(x + ((size_t)(b * TS + t) * DIN + d4 * 4));
  ushort4 o;
  o.x = (unsigned short)f2h_bits(v.x); o.y = (unsigned short)f2h_bits(v.y);
  o.z = (unsigned short)f2h_bits(v.z); o.w = (unsigned short)f2h_bits(v.w);
  *(ushort4*)(xh + ((size_t)(t * NB + b) * DIN + d4 * 4)) = o;
}

#define BARRIER() do { asm volatile("s_waitcnt lgkmcnt(0)" ::: "memory"); \
  __builtin_amdgcn_sched_barrier(0); __builtin_amdgcn_s_barrier(); \
  __builtin_amdgcn_sched_barrier(0); } while (0)

// ---- persistent bidirectional LSTM: both directions per WG, mutual latency hiding ----
__global__ __launch_bounds__(256, 1) void lstm_persist_k(
    const float* __restrict__ Wfw, const float* __restrict__ bfw, const float* __restrict__ pfw,
    const float* __restrict__ Wbw, const float* __restrict__ bbw, const float* __restrict__ pbw,
    const unsigned short* __restrict__ xh,
    u64* hb, float* __restrict__ out)
{
  __shared__ __align__(16) char AsF[NB * XROWB];   // 33,536 B fw x tile
  __shared__ __align__(16) char AsB[NB * XROWB];   // 33,536 B bw x tile
  __shared__ __align__(16) char Hst[NB * HROWB];   // 49,920 B h tile (time-shared fw/bw)
  __shared__ __align__(16) float Zs[4][NB][52];    // 26,624 B partials (time-shared)

  const int tid  = threadIdx.x;
  const int gg   = blockIdx.x;          // 0..63
  const int lane = tid & 63;
  const int wq   = tid >> 6;            // wave id = K-quarter stripe
  const int l15  = lane & 15;
  const int l4   = lane >> 4;           // 0..3
  const int ep   = tid & 7;
  const int eb   = tid >> 3;            // batch row 0..31
  const int u0   = gg * UPW;

  u64* hbF = hb;                        // dir 0: slots 0,1 (8192 u64 each)
  u64* hbB = hb + 16384;                // dir 1

  // ---- W fragments, 16x16x32 MFMA B-frags: [dir][col-tile][k-slice] (240 VGPR) ----
  // local col j = 16*ct + l15: gate = j&3, unit = u0 + 4*ct + (j>>2)
  f16x8 wfr[2][3][10];
#pragma unroll
  for (int d = 0; d < 2; ++d) {
    const float* W = d ? Wbw : Wfw;
#pragma unroll
    for (int ct = 0; ct < 3; ++ct) {
      const int gcol = (l15 & 3) * HU + u0 + 4 * ct + (l15 >> 2);
#pragma unroll
      for (int i = 0; i < 10; ++i) {
        const int k0 = (4 * i + wq) * 32 + l4 * 8;
#pragma unroll
        for (int j = 0; j < 8; ++j)
          wfr[d][ct][i][j] = (_Float16)W[(size_t)(k0 + j) * 3072 + gcol];
      }
    }
  }

  // ---- epilogue constants (ep<4 lanes own units u0+3ep..+3 per dir) ----
  float biF[3], bjF[3], bfF[3], boF[3], piF[3], pfF[3], poF[3], cstF[3];
  float biB[3], bjB[3], bfB[3], boB[3], piB[3], pfB[3], poB[3], cstB[3];
#pragma unroll
  for (int q = 0; q < 3; ++q) {
    int uu = 3 * ep + q; if (uu > 11) uu = 11;
    const int U = u0 + uu;
    biF[q] = bfw[U]; bjF[q] = bfw[HU + U]; bfF[q] = bfw[2 * HU + U]; boF[q] = bfw[3 * HU + U];
    piF[q] = pfw[U]; pfF[q] = pfw[HU + U]; poF[q] = pfw[2 * HU + U]; cstF[q] = 0.f;
    biB[q] = bbw[U]; bjB[q] = bbw[HU + U]; bfB[q] = bbw[2 * HU + U]; boB[q] = bbw[3 * HU + U];
    piB[q] = pbw[U]; pfB[q] = pbw[HU + U]; poB[q] = pbw[2 * HU + U]; cstB[q] = 0.f;
  }

  // Hs unpack base (producer-major decode; see word math in comments below)
  const int hsBase0 = HROWB * ((tid & 63) >> 1) + 24 * (tid >> 6) + 12 * (tid & 1);

  // ---- prologue: stage x_fw(0), x_bw(0) via global_load_lds; issue fw-h(0) loads ----
  {
    const unsigned short* xF = xh;                                  // t = 0
    const unsigned short* xB = xh + (size_t)(TS - 1) * (NB * DIN);  // t = TS-1
#pragma unroll
    for (int cc = 0; cc < 8; ++cc) {
      const int row = wq * 8 + cc;
      __builtin_amdgcn_global_load_lds((const gas_u32*)(xF + row * DIN + lane * 8),
                                       (las_u32*)(AsF + row * XROWB), 16, 0, 0);
      __builtin_amdgcn_global_load_lds((const gas_u32*)(xB + row * DIN + lane * 8),
                                       (las_u32*)(AsB + row * XROWB), 16, 0, 0);
    }
  }
  __builtin_amdgcn_sched_barrier(0);

  u32x4 hw[16];
  {
    const char* hp = (const char*)hbF + 16 * tid;   // slot 0
#pragma unroll
    for (int k = 0; k < 16; ++k)
      asm volatile("global_load_dwordx4 %0, %1, off sc0 sc1"
                   : "=v"(hw[k]) : "v"(hp + 4096 * k) : "memory");
  }
  __builtin_amdgcn_sched_barrier(0);

  for (int s = 0; s < TS; ++s) {
    const u32 tag  = (u32)s;
    const u32 ntag = (u32)(s + 1);
    const char* hpF = (const char*)(hbF + (size_t)(s & 1) * 8192) + 16 * tid;
    const char* hpB = (const char*)(hbB + (size_t)(s & 1) * 8192) + 16 * tid;
    u64* wdF = hbF + (size_t)((s + 1) & 1) * 8192;
    u64* wdB = hbB + (size_t)((s + 1) & 1) * 8192;

    // ==== P1: fw tag check (fw-h loads issued last iter P12 / prologue) ====
    if (s == 0) asm volatile("s_waitcnt vmcnt(0)" ::: "memory");
    else        asm volatile("s_waitcnt vmcnt(12)" ::: "memory");
    __builtin_amdgcn_sched_barrier(0);
    {
      u32 fresh = 0; int it = 0;
      while (true) {
        u32 stale = 0;
#pragma unroll
        for (int k = 0; k < 16; ++k) {
          if (!((fresh >> k) & 1)) {
            const u32 badk = ((hw[k][1] >> 16) ^ tag) | ((hw[k][3] >> 16) ^ tag);
            if (__all((int)(badk == 0))) fresh |= 1u << k; else stale |= 1u << k;
          }
        }
        if (stale == 0 || ++it >= SPIN_MAX) break;
        if (it > 2) __builtin_amdgcn_s_sleep(1);
#pragma unroll
        for (int k = 0; k < 16; ++k)
          if ((stale >> k) & 1)
            asm volatile("global_load_dwordx4 %0, %1, off sc0 sc1"
                         : "=v"(hw[k]) : "v"(hpF + 4096 * k) : "memory");
        asm volatile("s_waitcnt vmcnt(0)" ::: "memory");
        __builtin_amdgcn_sched_barrier(0);
      }
    }

    // ==== P2: fw unpack -> Hs (word w=512k+2tid: units 12*(4k+(tid>>6)) + 6*(tid&1)*... ) ====
#pragma unroll
    for (int k = 0; k < 16; ++k) {
      char* dp = Hst + hsBase0 + 96 * k;
      *(u32*)(dp)     = hw[k][0];
      *(u32*)(dp + 4) = (hw[k][1] & 0xFFFFu) | (hw[k][2] << 16);
      *(u32*)(dp + 8) = (hw[k][2] >> 16) | (hw[k][3] << 16);
    }
    __builtin_amdgcn_sched_barrier(0);

    // ==== P3: issue 16 bw-h(s) loads ====
#pragma unroll
    for (int k = 0; k < 16; ++k)
      asm volatile("global_load_dwordx4 %0, %1, off sc0 sc1"
                   : "=v"(hw[k]) : "v"(hpB + 4096 * k) : "memory");
    __builtin_amdgcn_sched_barrier(0);

    BARRIER();   // P5: Hs(fw) ready; AsF staged (own vmcnt ensured pre-barrier per wave)

    // ==== P6: fw MFMA -> Zs ====
    {
      f32x4 acc[2][3];
#pragma unroll
      for (int rb = 0; rb < 2; ++rb)
#pragma unroll
        for (int ct = 0; ct < 3; ++ct)
#pragma unroll
          for (int r = 0; r < 4; ++r) acc[rb][ct][r] = 0.f;
#pragma unroll
      for (int i = 0; i < 10; ++i) {
        const int c = 4 * i + wq;
#pragma unroll
        for (int rb = 0; rb < 2; ++rb) {
          const int row = rb * 16 + l15;
          const char* src = (c < 16) ? (AsF + row * XROWB + c * 64 + l4 * 16)
                                     : (Hst + row * HROWB + (c - 16) * 64 + l4 * 16);
          const f16x8 af = *(const f16x8*)src;
          acc[rb][0] = __builtin_amdgcn_mfma_f32_16x16x32_f16(af, wfr[0][0][i], acc[rb][0], 0, 0, 0);
          acc[rb][1] = __builtin_amdgcn_mfma_f32_16x16x32_f16(af, wfr[0][1][i], acc[rb][1], 0, 0, 0);
          acc[rb][2] = __builtin_amdgcn_mfma_f32_16x16x32_f16(af, wfr[0][2][i], acc[rb][2], 0, 0, 0);
        }
      }
      // C/D 16x16: col = lane&15, row = (lane>>4)*4 + r  [verified m89/m91]
#pragma unroll
      for (int rb = 0; rb < 2; ++rb)
#pragma unroll
        for (int ct = 0; ct < 3; ++ct)
#pragma unroll
          for (int r = 0; r < 4; ++r)
            Zs[wq][rb * 16 + l4 * 4 + r][16 * ct + l15] = acc[rb][ct][r];
    }
    BARRIER();   // P7: Zs(fw) ready; all AsF/Hs reads done

    // ==== P8: fw epilogue (ep<4) ====
    float hnF[3];
    if (ep < 4) {
#pragma unroll
      for (int q = 0; q < 3; ++q) {
        const int uu = 3 * ep + q;
        float zi = 0.f, zj = 0.f, zf = 0.f, zo = 0.f;
#pragma unroll
        for (int qq = 0; qq < 4; ++qq) {
          const float4 zp = *(const float4*)(&Zs[qq][eb][4 * uu]);
          zi += zp.x; zj += zp.y; zf += zp.z; zo += zp.w;
        }
        const float ig = 1.f / (1.f + __expf(-(zi + biF[q] + piF[q] * cstF[q])));
        const float fg = 1.f / (1.f + __expf(-(zf + bfF[q] + 1.f + pfF[q] * cstF[q])));
        const float jt = 1.f - 2.f / (__expf(2.f * (zj + bjF[q])) + 1.f);
        const float cn = fg * cstF[q] + ig * jt;
        const float og = 1.f / (1.f + __expf(-(zo + boF[q] + poF[q] * cn)));
        hnF[q] = og * (1.f - 2.f / (__expf(2.f * cn) + 1.f));
        cstF[q] = cn;
      }
    }
    __builtin_amdgcn_sched_barrier(0);

    // ==== P9: counted tail #1 (12 ops after bw-h): 8 AsF<-x_fw(s+1), fw pub, fw out x3 ====
    {
      const int tn = (s + 1 < TS) ? (s + 1) : (TS - 1);
      const unsigned short* xn = xh + (size_t)tn * (NB * DIN);
#pragma unroll
      for (int cc = 0; cc < 8; ++cc) {
        const int row = wq * 8 + cc;
        __builtin_amdgcn_global_load_lds((const gas_u32*)(xn + row * DIN + lane * 8),
                                         (las_u32*)(AsF + row * XROWB), 16, 0, 0);
      }
      if (ep < 4) {
        u32x2 pk;
        pk[0] = f2h_bits(hnF[0]) | (f2h_bits(hnF[1]) << 16);
        pk[1] = f2h_bits(hnF[2]) | (ntag << 16);
        const u64* wp = wdF + gg * 128 + eb * 4 + ep;
        asm volatile("global_store_dwordx2 %0, %1, off sc0 sc1" :: "v"(wp), "v"(pk) : "memory");
        float* op = out + ((size_t)eb * TS + s) * 1536 + u0 + 3 * ep;
        asm volatile("global_store_dword %0, %1, off" :: "v"(op), "v"(hnF[0]) : "memory");
        asm volatile("global_store_dword %0, %1, off" :: "v"(op + 1), "v"(hnF[1]) : "memory");
        asm volatile("global_store_dword %0, %1, off" :: "v"(op + 2), "v"(hnF[2]) : "memory");
      } else {
        // keep VMEM instruction count wave-uniform? (stores are wave-wide instrs with
        // exec mask; the 'if' above never has execz, so count is uniform already)
      }
    }
    __builtin_amdgcn_sched_barrier(0);

    // ==== P10: bw tag check (loads from P3; 12 counted ops after them) ====
    asm volatile("s_waitcnt vmcnt(12)" ::: "memory");
    __builtin_amdgcn_sched_barrier(0);
    {
      u32 fresh = 0; int it = 0;
      while (true) {
        u32 stale = 0;
#pragma unroll
        for (int k = 0; k < 16; ++k) {
          if (!((fresh >> k) & 1)) {
            const u32 badk = ((hw[k][1] >> 16) ^ tag) | ((hw[k][3] >> 16) ^ tag);
            if (__all((int)(badk == 0))) fresh |= 1u << k; else stale |= 1u << k;
          }
        }
        if (stale == 0 || ++it >= SPIN_MAX) break;
        if (it > 2) __builtin_amdgcn_s_sleep(1);
#pragma unroll
        for (int k = 0; k < 16; ++k)
          if ((stale >> k) & 1)
            asm volatile("global_load_dwordx4 %0, %1, off sc0 sc1"
                         : "=v"(hw[k]) : "v"(hpB + 4096 * k) : "memory");
        asm volatile("s_waitcnt vmcnt(0)" ::: "memory");
        __builtin_amdgcn_sched_barrier(0);
      }
    }

    // ==== P11: bw unpack -> Hs (fw reads finished at P7 barrier) ====
#pragma unroll
    for (int k = 0; k < 16; ++k) {
      char* dp = Hst + hsBase0 + 96 * k;
      *(u32*)(dp)     = hw[k][0];
      *(u32*)(dp + 4) = (hw[k][1] & 0xFFFFu) | (hw[k][2] << 16);
      *(u32*)(dp + 8) = (hw[k][2] >> 16) | (hw[k][3] << 16);
    }
    __builtin_amdgcn_sched_barrier(0);

    // ==== P12: issue 16 fw-h(s+1) loads ====
    {
      const char* hpFn = (const char*)(hbF + (size_t)((s + 1) & 1) * 8192) + 16 * tid;
#pragma unroll
      for (int k = 0; k < 16; ++k)
        asm volatile("global_load_dwordx4 %0, %1, off sc0 sc1"
                     : "=v"(hw[k]) : "v"(hpFn + 4096 * k) : "memory");
    }
    __builtin_amdgcn_sched_barrier(0);

    BARRIER();   // P13: Hs(bw) ready; Zs(fw) fully consumed (P8 readers passed)

    // ==== P14: bw MFMA -> Zs ====
    {
      f32x4 acc[2][3];
#pragma unroll
      for (int rb = 0; rb < 2; ++rb)
#pragma unroll
        for (int ct = 0; ct < 3; ++ct)
#pragma unroll
          for (int r = 0; r < 4; ++r) acc[rb][ct][r] = 0.f;
#pragma unroll
      for (int i = 0; i < 10; ++i) {
        const int c = 4 * i + wq;
#pragma unroll
        for (int rb = 0; rb < 2; ++rb) {
          const int row = rb * 16 + l15;
          const char* src = (c < 16) ? (AsB + row * XROWB + c * 64 + l4 * 16)
                                     : (Hst + row * HROWB + (c - 16) * 64 + l4 * 16);
          const f16x8 af = *(const f16x8*)src;
          acc[rb][0] = __builtin_amdgcn_mfma_f32_16x16x32_f16(af, wfr[1][0][i], acc[rb][0], 0, 0, 0);
          acc[rb][1] = __builtin_amdgcn_mfma_f32_16x16x32_f16(af, wfr[1][1][i], acc[rb][1], 0, 0, 0);
          acc[rb][2] = __builtin_amdgcn_mfma_f32_16x16x32_f16(af, wfr[1][2][i], acc[rb][2], 0, 0, 0);
        }
      }
#pragma unroll
      for (int rb = 0; rb < 2; ++rb)
#pragma unroll
        for (int ct = 0; ct < 3; ++ct)
#pragma unroll
          for (int r = 0; r < 4; ++r)
            Zs[wq][rb * 16 + l4 * 4 + r][16 * ct + l15] = acc[rb][ct][r];
    }
    BARRIER();   // P15: Zs(bw) ready; all AsB/Hs reads done

    // ==== P16: bw epilogue; counted tail #2 (12 ops after fw-h): 8 AsB stage, pub, out x3 ====
    {
      const int tb = TS - 1 - s;
      float hnB[3];
      if (ep < 4) {
#pragma unroll
        for (int q = 0; q < 3; ++q) {
          const int uu = 3 * ep + q;
          float zi = 0.f, zj = 0.f, zf = 0.f, zo = 0.f;
#pragma unroll
          for (int qq = 0; qq < 4; ++qq) {
            const float4 zp = *(const float4*)(&Zs[qq][eb][4 * uu]);
            zi += zp.x; zj += zp.y; zf += zp.z; zo += zp.w;
          }
          const float ig = 1.f / (1.f + __expf(-(zi + biB[q] + piB[q] * cstB[q])));
          const float fg = 1.f / (1.f + __expf(-(zf + bfB[q] + 1.f + pfB[q] * cstB[q])));
          const float jt = 1.f - 2.f / (__expf(2.f * (zj + bjB[q])) + 1.f);
          const float cn = fg * cstB[q] + ig * jt;
          const float og = 1.f / (1.f + __expf(-(zo + boB[q] + poB[q] * cn)));
          hnB[q] = og * (1.f - 2.f / (__expf(2.f * cn) + 1.f));
          cstB[q] = cn;
        }
      }
      __builtin_amdgcn_sched_barrier(0);
      const int tn = (s + 1 < TS) ? (TS - 2 - s) : 0;
      const unsigned short* xn = xh + (size_t)tn * (NB * DIN);
#pragma unroll
      for (int cc = 0; cc < 8; ++cc) {
        const int row = wq * 8 + cc;
        __builtin_amdgcn_global_load_lds((const gas_u32*)(xn + row * DIN + lane * 8),
                                         (las_u32*)(AsB + row * XROWB), 16, 0, 0);
      }
      if (ep < 4) {
        u32x2 pk;
        pk[0] = f2h_bits(hnB[0]) | (f2h_bits(hnB[1]) << 16);
        pk[1] = f2h_bits(hnB[2]) | (ntag << 16);
        const u64* wp = wdB + gg * 128 + eb * 4 + ep;
        asm volatile("global_store_dwordx2 %0, %1, off sc0 sc1" :: "v"(wp), "v"(pk) : "memory");
        float* op = out + ((size_t)eb * TS + tb) * 1536 + HU + u0 + 3 * ep;
        asm volatile("global_store_dword %0, %1, off" :: "v"(op), "v"(hnB[0]) : "memory");
        asm volatile("global_store_dword %0, %1, off" :: "v"(op + 1), "v"(hnB[1]) : "memory");
        asm volatile("global_store_dword %0, %1, off" :: "v"(op + 2), "v"(hnB[2]) : "memory");
      }
    }
    __builtin_amdgcn_sched_barrier(0);
  }
}

extern "C" void kernel_launch(void* const* d_in, const int* in_sizes, int n_in,
                              void* d_out, int out_size, void* d_ws, size_t ws_size,
                              hipStream_t stream) {
  const float* x   = (const float*)d_in[0];
  const float* Wfw = (const float*)d_in[1];
  const float* bfw = (const float*)d_in[2];
  const float* pfw = (const float*)d_in[3];
  const float* Wbw = (const float*)d_in[4];
  const float* bbw = (const float*)d_in[5];
  const float* pbw = (const float*)d_in[6];
  float* out = (float*)d_out;

  char* ws = (char*)d_ws;
  unsigned short* xh = (unsigned short*)ws;              // 33,554,432 B
  u64* hb            = (u64*)(ws + 33554432);            //    262,144 B

  lstm_init_k<<<128, 256, 0, stream>>>(hb);
  lstm_xpose_k<<<16384, 256, 0, stream>>>(x, xh);
  lstm_persist_k<<<dim3(64), dim3(256), 0, stream>>>(Wfw, bfw, pfw, Wbw, bbw, pbw,
                                                     xh, hb, out);
}

// Round 13
// 6459.206 us; speedup vs baseline: 1.5968x; 1.5968x over previous
//
#include <hip/hip_runtime.h>
#include <stdint.h>

#define TS    1024
#define NB    32
#define DIN   512
#define HU    768
#define XPADB 1040      // As row stride bytes (512 fp16 + 16B pad)
#define HPADB 1552      // Hs row stride bytes (768 fp16 + 16B pad)

typedef _Float16 f16x8 __attribute__((ext_vector_type(8)));
typedef float f32x4 __attribute__((ext_vector_type(4)));
typedef unsigned int u32;
typedef u32 u32x4 __attribute__((ext_vector_type(4)));
using gas_u32 = u32 __attribute__((address_space(1)));
using las_u32 = u32 __attribute__((address_space(3)));

__device__ __forceinline__ unsigned short f2h(float f) {
  _Float16 h = (_Float16)f;
  return __builtin_bit_cast(unsigned short, h);
}

// ---- init: zero h slot0 (98,304 B) + c state (196,608 B); re-run every launch ----
__global__ void lstm_init_k(u32* hb, u32* cb) {
  int i = blockIdx.x * 256 + threadIdx.x;
  if (i < 24576) hb[i] = 0u;
  else if (i < 73728) cb[i - 24576] = 0u;
}

// ---- transpose + fp16: x[B][T][D] -> xh[T][B][D] ----
__global__ void lstm_xpose_k(const float* __restrict__ x, unsigned short* __restrict__ xh) {
  int idx = blockIdx.x * 256 + threadIdx.x;
  int d4 = idx & 127;
  int t  = (idx >> 7) & 1023;
  int b  = idx >> 17;
  float4 v = *(const float4*)(x + ((size_t)(b * TS + t) * DIN + d4 * 4));
  ushort4 o;
  o.x = f2h(v.x); o.y = f2h(v.y); o.z = f2h(v.z); o.w = f2h(v.w);
  *(ushort4*)(xh + ((size_t)(t * NB + b) * DIN + d4 * 4)) = o;
}

// ---- pack W (fp32 [1280][3072]) into MFMA-fragment order, fp16, coalesced streams ----
// Wpk element for (d, wt, i, lane, j): W[i*32 + (lane>>4)*8 + j][(l15&3)*768 + wt*4 + (l15>>2)]
__global__ void lstm_wpack_k(const float* __restrict__ Wfw, const float* __restrict__ Wbw,
                             unsigned short* __restrict__ Wpk) {
  __shared__ unsigned short Ls[20480];
  const int wg = blockIdx.x;            // 0..383 = d*192 + wt
  const int d  = wg / 192;
  const int wt = wg % 192;
  const float* W = d ? Wbw : Wfw;
  const int t = threadIdx.x;
#pragma unroll 4
  for (int m = 0; m < 80; ++m) {
    const int e = t + 256 * m;          // 1280 k x 16 cols
    const int u = e & 3, g = (e >> 2) & 3, k = e >> 4;
    const int gcol = g * HU + wt * 4 + u;
    const float v = W[(size_t)k * 3072 + gcol];
    const int l15 = u * 4 + g, l4 = (k >> 3) & 3, j = k & 7, i = k >> 5;
    Ls[i * 512 + (l4 * 16 + l15) * 8 + j] = f2h(v);
  }
  __syncthreads();
  unsigned short* dst = Wpk + (size_t)wg * 20480;
#pragma unroll
  for (int m = 0; m < 10; ++m) {
    const int c16 = t + 256 * m;        // 2560 16B-chunks
    *(u32x4*)(dst + c16 * 8) = *(const u32x4*)(Ls + c16 * 8);
  }
}

// ---- one LSTM step, both directions; no inter-WG communication ----
__global__ __launch_bounds__(256) void lstm_step_k(
    const unsigned short* __restrict__ xh, const unsigned short* __restrict__ Wpk,
    const float* __restrict__ bfw, const float* __restrict__ pfw,
    const float* __restrict__ bbw, const float* __restrict__ pbw,
    unsigned short* __restrict__ hb, float* __restrict__ cb,
    float* __restrict__ out, int s)
{
  __shared__ __align__(16) char As[NB * XPADB];   // 33,280 B x tile
  __shared__ __align__(16) char Hs[NB * HPADB];   // 49,664 B h tile
  __shared__ __align__(16) float Zw[4][NB][20];   // 10,240 B per-wave z

  const int blk = blockIdx.x;
  const int dir = (blk >= 48) ? 1 : 0;
  const int db  = dir ? (blk - 48) : blk;         // 0..47
  const int ub  = db * 16;                        // unit base of WG
  const int tid = threadIdx.x, lane = tid & 63, wq = tid >> 6;
  const int l15 = lane & 15, l4 = lane >> 4;
  const int t   = dir ? (TS - 1 - s) : s;

  const unsigned short* hsrc = hb + (size_t)(s & 1) * 49152 + dir * 24576;
  unsigned short*       hdst = hb + (size_t)((s + 1) & 1) * 49152 + dir * 24576;
  const float* bias = dir ? bbw : bfw;
  const float* peep = dir ? pbw : pfw;

  // ---- stage x rows via global_load_lds (8 rows per wave, 1 call/row) ----
#pragma unroll
  for (int cc = 0; cc < 8; ++cc) {
    const int row = wq * 8 + cc;
    __builtin_amdgcn_global_load_lds(
        (const gas_u32*)(xh + ((size_t)t * NB + row) * DIN + lane * 8),
        (las_u32*)(As + row * XPADB), 16, 0, 0);
  }
  // ---- h loads (coalesced 16B/thread x 12) ----
  u32x4 hv[12];
#pragma unroll
  for (int jj = 0; jj < 12; ++jj) {
    const int idx16 = tid + 256 * jj;             // 3072 chunks = 48 KB
    hv[jj] = *(const u32x4*)((const char*)hsrc + idx16 * 16);
  }
  // ---- W stream base + preload first 8 frags ----
  const char* wbase = (const char*)Wpk + (size_t)(dir * 192 + db * 4 + wq) * 40960;
  f16x8 wfa[8], wfb[8];
#pragma unroll
  for (int i = 0; i < 8; ++i)
    wfa[i] = *(const f16x8*)(wbase + i * 1024 + lane * 16);

  // ---- epilogue constants: 2 cells (b = lane&31, units U0, U0+1) ----
  const int b  = lane & 31;
  const int pr = lane >> 5;
  const int U0 = ub + wq * 4 + pr * 2;
  const float bi0 = bias[U0],          bi1 = bias[U0 + 1];
  const float bj0 = bias[HU + U0],     bj1 = bias[HU + U0 + 1];
  const float bf0 = bias[2*HU + U0],   bf1 = bias[2*HU + U0 + 1];
  const float bo0 = bias[3*HU + U0],   bo1 = bias[3*HU + U0 + 1];
  const float pi0 = peep[U0],          pi1 = peep[U0 + 1];
  const float pf0 = peep[HU + U0],     pf1 = peep[HU + U0 + 1];
  const float po0 = peep[2*HU + U0],   po1 = peep[2*HU + U0 + 1];
  float* cp = cb + ((size_t)(dir * NB + b) * HU + U0);
  const float c0 = cp[0], c1 = cp[1];

  // ---- h -> Hs ----
#pragma unroll
  for (int jj = 0; jj < 12; ++jj) {
    const int idx16 = tid + 256 * jj;
    const int row = idx16 / 96, c16 = idx16 % 96;
    *(u32x4*)(Hs + row * HPADB + c16 * 16) = hv[jj];
  }
  __syncthreads();   // drains gload_lds (vmcnt) + ds writes

  // ---- MFMA: 40 K-slices x 2 row-blocks, W double-buffered 8-deep ----
  f32x4 acc0, acc1;
#pragma unroll
  for (int r = 0; r < 4; ++r) { acc0[r] = 0.f; acc1[r] = 0.f; }
#pragma unroll
  for (int blkI = 0; blkI < 5; ++blkI) {
    if (blkI < 4) {
#pragma unroll
      for (int ii = 0; ii < 8; ++ii) {
        const int inext = (blkI + 1) * 8 + ii;
        if (blkI & 1) wfa[ii] = *(const f16x8*)(wbase + inext * 1024 + lane * 16);
        else          wfb[ii] = *(const f16x8*)(wbase + inext * 1024 + lane * 16);
      }
    }
#pragma unroll
    for (int ii = 0; ii < 8; ++ii) {
      const int i = blkI * 8 + ii;
      const char* abase = (i < 16) ? (As + i * 64) : (Hs + (i - 16) * 64);
      const int   rstr  = (i < 16) ? XPADB : HPADB;
      const f16x8 wf = (blkI & 1) ? wfb[ii] : wfa[ii];
      const f16x8 af0 = *(const f16x8*)(abase + l15 * rstr + l4 * 16);
      acc0 = __builtin_amdgcn_mfma_f32_16x16x32_f16(af0, wf, acc0, 0, 0, 0);
      const f16x8 af1 = *(const f16x8*)(abase + (16 + l15) * rstr + l4 * 16);
      acc1 = __builtin_amdgcn_mfma_f32_16x16x32_f16(af1, wf, acc1, 0, 0, 0);
    }
  }

  // ---- z -> Zw (C/D 16x16: col=lane&15, row=(lane>>4)*4+r; verified) ----
#pragma unroll
  for (int r = 0; r < 4; ++r) {
    Zw[wq][l4 * 4 + r][l15]      = acc0[r];
    Zw[wq][16 + l4 * 4 + r][l15] = acc1[r];
  }
  asm volatile("s_waitcnt lgkmcnt(0)" ::: "memory");   // same-wave RAW only
  __builtin_amdgcn_sched_barrier(0);

  // ---- epilogue: 2 cells ----
  float hn0, hn1;
  {
    const float4 zp = *(const float4*)(&Zw[wq][b][4 * (pr * 2)]);
    const float ig = 1.f / (1.f + __expf(-(zp.x + bi0 + pi0 * c0)));
    const float fg = 1.f / (1.f + __expf(-(zp.z + bf0 + 1.f + pf0 * c0)));
    const float jt = 1.f - 2.f / (__expf(2.f * (zp.y + bj0)) + 1.f);
    const float cn = fg * c0 + ig * jt;
    const float og = 1.f / (1.f + __expf(-(zp.w + bo0 + po0 * cn)));
    hn0 = og * (1.f - 2.f / (__expf(2.f * cn) + 1.f));
    cp[0] = cn;
  }
  {
    const float4 zp = *(const float4*)(&Zw[wq][b][4 * (pr * 2 + 1)]);
    const float ig = 1.f / (1.f + __expf(-(zp.x + bi1 + pi1 * c1)));
    const float fg = 1.f / (1.f + __expf(-(zp.z + bf1 + 1.f + pf1 * c1)));
    const float jt = 1.f - 2.f / (__expf(2.f * (zp.y + bj1)) + 1.f);
    const float cn = fg * c1 + ig * jt;
    const float og = 1.f / (1.f + __expf(-(zp.w + bo1 + po1 * cn)));
    hn1 = og * (1.f - 2.f / (__expf(2.f * cn) + 1.f));
    cp[1] = cn;
  }
  // h out (fp16 pair, 4B) + out (f32 pair, 8B)
  *(u32*)(hdst + (size_t)b * HU + U0) = (u32)f2h(hn0) | ((u32)f2h(hn1) << 16);
  float* op = out + ((size_t)b * TS + t) * 1536 + dir * HU + U0;
  op[0] = hn0; op[1] = hn1;
}

extern "C" void kernel_launch(void* const* d_in, const int* in_sizes, int n_in,
                              void* d_out, int out_size, void* d_ws, size_t ws_size,
                              hipStream_t stream) {
  const float* x   = (const float*)d_in[0];
  const float* Wfw = (const float*)d_in[1];
  const float* bfw = (const float*)d_in[2];
  const float* pfw = (const float*)d_in[3];
  const float* Wbw = (const float*)d_in[4];
  const float* bbw = (const float*)d_in[5];
  const float* pbw = (const float*)d_in[6];
  float* out = (float*)d_out;

  char* ws = (char*)d_ws;
  unsigned short* xh  = (unsigned short*)ws;                      // 33,554,432 B
  unsigned short* Wpk = (unsigned short*)(ws + 33554432);         // 15,728,640 B
  unsigned short* hb  = (unsigned short*)(ws + 49283072);         //    196,608 B
  float*          cb  = (float*)(ws + 49479680);                  //    196,608 B

  lstm_init_k<<<288, 256, 0, stream>>>((u32*)hb, (u32*)cb);
  lstm_xpose_k<<<16384, 256, 0, stream>>>(x, xh);
  lstm_wpack_k<<<384, 256, 0, stream>>>(Wfw, Wbw, Wpk);
  for (int s = 0; s < TS; ++s) {
    lstm_step_k<<<96, 256, 0, stream>>>(xh, Wpk, bfw, pfw, bbw, pbw, hb, cb, out, s);
  }
}